// Round 1
// baseline (491.340 us; speedup 1.0000x reference)
//
#include <hip/hip_runtime.h>

// Problem constants (B=64 batches, n=64 nodes/batch, H=128, epg=2048 edges/batch)
#define NB 64
#define NPB 64
#define HD 128
#define EPB 2048
#define NNODE 4096     // NB*NPB
#define KK 52          // ceil(0.8*64)
#define NKOUT 3328     // NB*KK
#define NEG 0.01f

__device__ __forceinline__ float lrelu(float v){ return v > 0.f ? v : NEG*v; }

// ---------------- zero-fill (A2 off-block region) ----------------
__global__ void k_zero4(float4* __restrict__ p, int n4){
  int i = blockIdx.x*256 + threadIdx.x;
  if (i < n4) p[i] = make_float4(0.f,0.f,0.f,0.f);
}

// ---------------- build dense per-batch A (normalized) + multiplicity M ----------------
__global__ __launch_bounds__(256) void k_build(const int* __restrict__ ei, const float* __restrict__ w,
                                               float* __restrict__ A_g, float* __restrict__ M_g){
  __shared__ float Ws[4096];
  __shared__ float Mc[4096];
  __shared__ float dv[64];
  int b = blockIdx.x, tid = threadIdx.x;
  for (int i = tid; i < 4096; i += 256){ Ws[i] = 0.f; Mc[i] = 0.f; }
  __syncthreads();
  const int* r0 = ei + b*EPB;
  const int* c0 = ei + NB*EPB + b*EPB;
  const float* w0 = w + b*EPB;
  int base = b*NPB;
  for (int e = tid; e < EPB; e += 256){
    int r = r0[e] - base, c = c0[e] - base;
    atomicAdd(&Ws[r*64 + c], w0[e]);
    atomicAdd(&Mc[r*64 + c], 1.f);
  }
  if (tid < 64){ atomicAdd(&Ws[tid*64 + tid], 1.f); atomicAdd(&Mc[tid*64 + tid], 1.f); }
  __syncthreads();
  if (tid < 64){
    float d = 0.f;
    for (int r = 0; r < 64; r++) d += Ws[r*64 + tid];   // deg over col
    dv[tid] = d > 0.f ? rsqrtf(fmaxf(d, 1e-12f)) : 0.f;
  }
  __syncthreads();
  for (int i = tid; i < 4096; i += 256){
    int r = i >> 6, c = i & 63;
    A_g[b*4096 + i] = dv[r]*Ws[i]*dv[c];
    M_g[b*4096 + i] = Mc[i];
  }
}

// ---------------- double hop: out = A^T (A^T v), per-batch ----------------
__global__ __launch_bounds__(256) void k_hop2(const float* __restrict__ A_g, const float* __restrict__ v_in,
                                              float* __restrict__ v_out){
  __shared__ float A[4096];
  __shared__ float V[8192];
  int b = blockIdx.x, tid = threadIdx.x;
  for (int i = tid; i < 4096; i += 256) A[i] = A_g[b*4096 + i];
  for (int i = tid; i < 8192; i += 256) V[i] = v_in[b*8192 + i];
  __syncthreads();
  int f = tid & 127, cg = tid >> 7;
  float tmp[32];
  #pragma unroll
  for (int j = 0; j < 32; j++){
    int c = cg + 2*j;
    float acc = 0.f;
    for (int r = 0; r < 64; r++) acc += A[r*64 + c]*V[r*128 + f];
    tmp[j] = acc;
  }
  __syncthreads();
  #pragma unroll
  for (int j = 0; j < 32; j++){ int c = cg + 2*j; V[c*128 + f] = tmp[j]; }
  __syncthreads();
  #pragma unroll
  for (int j = 0; j < 32; j++){
    int c = cg + 2*j;
    float acc = 0.f;
    for (int r = 0; r < 64; r++) acc += A[r*64 + c]*V[r*128 + f];
    v_out[b*8192 + c*128 + f] = acc;
  }
}

// ---------------- generic fp32 GEMM: C = act(A @ W), 64x64 tiles, z-batched ----------------
__global__ __launch_bounds__(256) void k_gemm(const float* __restrict__ A, const float* __restrict__ W,
                                              float* __restrict__ C, int K, int M,
                                              long az, long wz, long cz, int leaky){
  int z = blockIdx.z;
  A += (size_t)z*az; W += (size_t)z*wz; C += (size_t)z*cz;
  __shared__ __align__(16) float As[16][68];
  __shared__ __align__(16) float Bs[16][68];
  int tid = threadIdx.x, tx = tid & 15, ty = tid >> 4;
  int i0 = blockIdx.y*64, j0 = blockIdx.x*64;
  float acc[4][4] = {};
  for (int k0 = 0; k0 < K; k0 += 16){
    int r = tid >> 2, c4 = (tid & 3)*4;
    float4 av = *(const float4*)(A + (size_t)(i0 + r)*K + k0 + c4);
    As[c4+0][r] = av.x; As[c4+1][r] = av.y; As[c4+2][r] = av.z; As[c4+3][r] = av.w;
    int wr = tid >> 4, wc4 = (tid & 15)*4;
    *(float4*)&Bs[wr][wc4] = *(const float4*)(W + (size_t)(k0 + wr)*M + j0 + wc4);
    __syncthreads();
    #pragma unroll
    for (int k = 0; k < 16; k++){
      float4 a4 = *(const float4*)&As[k][ty*4];
      float4 b4 = *(const float4*)&Bs[k][tx*4];
      float a_[4] = {a4.x, a4.y, a4.z, a4.w};
      float b_[4] = {b4.x, b4.y, b4.z, b4.w};
      #pragma unroll
      for (int ii = 0; ii < 4; ii++)
        #pragma unroll
        for (int jj = 0; jj < 4; jj++)
          acc[ii][jj] += a_[ii]*b_[jj];
    }
    __syncthreads();
  }
  #pragma unroll
  for (int ii = 0; ii < 4; ii++){
    int gi = i0 + ty*4 + ii;
    float4 o;
    o.x = acc[ii][0]; o.y = acc[ii][1]; o.z = acc[ii][2]; o.w = acc[ii][3];
    if (leaky){ o.x = lrelu(o.x); o.y = lrelu(o.y); o.z = lrelu(o.z); o.w = lrelu(o.w); }
    *(float4*)(C + (size_t)gi*M + j0 + tx*4) = o;
  }
}

// ---------------- W1 GEMM with h=[a,q,a-q,a*q] synthesized in staging (K=512, M=256) ----------------
// z=0: query = q0 (per-node, N x H). z=1: query = tgt[batch] broadcast (64 x H).
__global__ __launch_bounds__(256) void k_gemm_h(const float* __restrict__ a_buf, const float* __restrict__ q0,
                                                const float* __restrict__ tgt, const float* __restrict__ W1,
                                                float* __restrict__ C){
  int z = blockIdx.z;
  const float* A = a_buf + (size_t)z*NNODE*HD;
  const float* W = W1 + (size_t)z*512*256;
  float* Cz = C + (size_t)z*NNODE*256;
  __shared__ __align__(16) float As[16][68];
  __shared__ __align__(16) float Bs[16][68];
  int tid = threadIdx.x, tx = tid & 15, ty = tid >> 4;
  int i0 = blockIdx.y*64, j0 = blockIdx.x*64;
  float acc[4][4] = {};
  for (int k0 = 0; k0 < 512; k0 += 16){
    int seg = k0 >> 7, kk = k0 & 127;
    int r = tid >> 2, c4 = (tid & 3)*4;
    int gi = i0 + r;
    float4 hv;
    if (seg == 0){
      hv = *(const float4*)(A + (size_t)gi*HD + kk + c4);
    } else if (seg == 1){
      hv = (z == 0) ? *(const float4*)(q0 + (size_t)gi*HD + kk + c4)
                    : *(const float4*)(tgt + (size_t)(gi >> 6)*HD + kk + c4);
    } else {
      float4 avv = *(const float4*)(A + (size_t)gi*HD + kk + c4);
      float4 qv = (z == 0) ? *(const float4*)(q0 + (size_t)gi*HD + kk + c4)
                           : *(const float4*)(tgt + (size_t)(gi >> 6)*HD + kk + c4);
      if (seg == 2){ hv.x = avv.x - qv.x; hv.y = avv.y - qv.y; hv.z = avv.z - qv.z; hv.w = avv.w - qv.w; }
      else         { hv.x = avv.x * qv.x; hv.y = avv.y * qv.y; hv.z = avv.z * qv.z; hv.w = avv.w * qv.w; }
    }
    As[c4+0][r] = hv.x; As[c4+1][r] = hv.y; As[c4+2][r] = hv.z; As[c4+3][r] = hv.w;
    int wr = tid >> 4, wc4 = (tid & 15)*4;
    *(float4*)&Bs[wr][wc4] = *(const float4*)(W + (size_t)(k0 + wr)*256 + j0 + wc4);
    __syncthreads();
    #pragma unroll
    for (int k = 0; k < 16; k++){
      float4 a4 = *(const float4*)&As[k][ty*4];
      float4 b4 = *(const float4*)&Bs[k][tx*4];
      float a_[4] = {a4.x, a4.y, a4.z, a4.w};
      float b_[4] = {b4.x, b4.y, b4.z, b4.w};
      #pragma unroll
      for (int ii = 0; ii < 4; ii++)
        #pragma unroll
        for (int jj = 0; jj < 4; jj++)
          acc[ii][jj] += a_[ii]*b_[jj];
    }
    __syncthreads();
  }
  #pragma unroll
  for (int ii = 0; ii < 4; ii++){
    int gi = i0 + ty*4 + ii;
    float4 o;
    o.x = lrelu(acc[ii][0]); o.y = lrelu(acc[ii][1]); o.z = lrelu(acc[ii][2]); o.w = lrelu(acc[ii][3]);
    *(float4*)(Cz + (size_t)gi*256 + j0 + tx*4) = o;
  }
}

// ---------------- final MLP layer: logit = leaky(h2 . W3), one wave per row ----------------
__global__ __launch_bounds__(256) void k_w3(const float* __restrict__ h2, const float* __restrict__ W3,
                                            float* __restrict__ logit){
  int z = blockIdx.z;
  int wave = threadIdx.x >> 6, lane = threadIdx.x & 63;
  int row = blockIdx.x*4 + wave;
  const float* h = h2 + ((size_t)z*NNODE + row)*HD;
  const float* w = W3 + (size_t)z*HD;
  float v = h[lane]*w[lane] + h[lane + 64]*w[lane + 64];
  #pragma unroll
  for (int off = 32; off; off >>= 1) v += __shfl_down(v, off);
  if (lane == 0) logit[z*NNODE + row] = lrelu(v);
}

// ---------------- per-batch softmax over 64 logits ----------------
__global__ void k_softmax(const float* __restrict__ logit, float* __restrict__ f){
  int z = blockIdx.z, b = blockIdx.x, lane = threadIdx.x;
  float l = logit[z*NNODE + b*64 + lane];
  float m = l;
  #pragma unroll
  for (int off = 32; off; off >>= 1) m = fmaxf(m, __shfl_xor(m, off));
  float e = expf(l - m);
  float s = e;
  #pragma unroll
  for (int off = 32; off; off >>= 1) s += __shfl_xor(s, off);
  f[z*NNODE + b*64 + lane] = e/s;
}

// ---------------- cluster score: softmax over batch of (g1+g2) ----------------
__global__ void k_score(const float* __restrict__ g, float* __restrict__ score){
  int b = blockIdx.x, lane = threadIdx.x;
  float l = g[b*64 + lane] + g[NNODE + b*64 + lane];
  float m = l;
  #pragma unroll
  for (int off = 32; off; off >>= 1) m = fmaxf(m, __shfl_xor(m, off));
  float e = expf(l - m);
  float s = e;
  #pragma unroll
  for (int off = 32; off; off >>= 1) s += __shfl_xor(s, off);
  score[b*64 + lane] = e/s;
}

// ---------------- edge softmax (multiplicity-weighted) + S + agg ----------------
__global__ __launch_bounds__(256) void k_edge(const float* __restrict__ M_g, const float* __restrict__ fb,
                                              const float* __restrict__ x, float* __restrict__ S_g,
                                              float* __restrict__ agg){
  __shared__ float Mc[4096];   // in: multiplicity, out (in-place): Ew = M*E
  __shared__ float xb[8192];
  __shared__ float f1s[64], f2s[64];
  int b = blockIdx.x, tid = threadIdx.x;
  for (int i = tid; i < 4096; i += 256) Mc[i] = M_g[b*4096 + i];
  for (int i = tid; i < 8192; i += 256) xb[i] = x[b*8192 + i];
  if (tid < 64) f1s[tid] = fb[b*64 + tid];
  else if (tid < 128) f2s[tid - 64] = fb[NNODE + b*64 + (tid - 64)];
  __syncthreads();
  int c = tid >> 2, sub = tid & 3;   // 4 lanes per column
  float m = -1e30f;
  for (int r = sub; r < 64; r += 4)
    if (Mc[r*64 + c] > 0.f) m = fmaxf(m, lrelu(f1s[c] + f2s[r]));
  m = fmaxf(m, __shfl_xor(m, 1));
  m = fmaxf(m, __shfl_xor(m, 2));
  float s = 0.f;
  for (int r = sub; r < 64; r += 4){
    float mc = Mc[r*64 + c];
    if (mc > 0.f) s += mc*expf(lrelu(f1s[c] + f2s[r]) - m);
  }
  s += __shfl_xor(s, 1);
  s += __shfl_xor(s, 2);
  for (int r = sub; r < 64; r += 4){
    float mc = Mc[r*64 + c];
    float v = 0.f;
    if (mc > 0.f) v = mc*expf(lrelu(f1s[c] + f2s[r]) - m)/s;
    Mc[r*64 + c] = v;
  }
  __syncthreads();
  for (int i = tid; i < 4096; i += 256) S_g[b*4096 + i] = Mc[i];
  int f = tid & 127, cg = tid >> 7;
  for (int cc = cg; cc < 64; cc += 2){
    float acc = 0.f;
    for (int r = 0; r < 64; r++) acc += Mc[r*64 + cc]*xb[r*128 + f];
    agg[b*8192 + cc*128 + f] = acc;
  }
}

// ---------------- x_c = 0.5*(leaky(x+y0)+leaky(x+y1)) ----------------
__global__ void k_xc(const float* __restrict__ x, const float* __restrict__ y, float* __restrict__ xc){
  int i = blockIdx.x*256 + threadIdx.x;
  float xv = x[i];
  xc[i] = 0.5f*(lrelu(xv + y[i]) + lrelu(xv + y[NNODE*HD + i]));
}

// ---------------- exact top-52 per batch, descending, lowest-index tie-break ----------------
__global__ void k_topk(const float* __restrict__ score, int* __restrict__ perm_int, int* __restrict__ pidx,
                       float* __restrict__ out_batch, float* __restrict__ out_perm){
  int b = blockIdx.x, lane = threadIdx.x;
  float s = score[b*64 + lane];
  for (int t = 0; t < KK; t++){
    float v = s; int idx = lane;
    #pragma unroll
    for (int off = 32; off; off >>= 1){
      float ov = __shfl_xor(v, off); int oi = __shfl_xor(idx, off);
      if (ov > v || (ov == v && oi < idx)){ v = ov; idx = oi; }
    }
    if (lane == 0){
      perm_int[b*KK + t] = b*64 + idx;
      pidx[b*KK + t] = idx;
      out_batch[b*KK + t] = (float)b;
      out_perm[b*KK + t] = (float)(b*64 + idx);
    }
    if (lane == idx) s = -1e30f;
  }
}

// ---------------- x_out = x[perm]*score[perm] ----------------
__global__ void k_xout(const float* __restrict__ x, const float* __restrict__ score,
                       const int* __restrict__ perm_int, float* __restrict__ out){
  int g = blockIdx.x*256 + threadIdx.x;   // 425984 total
  int j = g >> 7, f = g & 127;
  int p = perm_int[j];
  out[g] = x[p*128 + f]*score[p];
}

// ---------------- per-batch A2 block: S_p^T (A S_p), diag=1 ----------------
__global__ __launch_bounds__(256) void k_A2(const float* __restrict__ A_g, const float* __restrict__ S_g,
                                            const int* __restrict__ pidx, float* __restrict__ outA2){
  __shared__ float A[4096];
  __shared__ float S[4096];
  __shared__ float T[64][56];
  __shared__ int pc[KK];
  int b = blockIdx.x, tid = threadIdx.x;
  for (int i = tid; i < 4096; i += 256){ A[i] = A_g[b*4096 + i]; S[i] = S_g[b*4096 + i]; }
  if (tid < KK) pc[tid] = pidx[b*KK + tid];
  __syncthreads();
  for (int o = tid; o < 64*KK; o += 256){
    int i = o/KK, t = o - i*KK;
    int ct = pc[t];
    float acc = 0.f;
    for (int k = 0; k < 64; k++) acc += A[i*64 + k]*S[k*64 + ct];
    T[i][t] = acc;
  }
  __syncthreads();
  for (int o = tid; o < KK*KK; o += 256){
    int a = o/KK, t = o - a*KK;
    float v;
    if (a == t) v = 1.f;
    else {
      int pa = pc[a];
      v = 0.f;
      for (int i2 = 0; i2 < 64; i2++) v += S[i2*64 + pa]*T[i2][t];
    }
    outA2[(size_t)(b*KK + a)*NKOUT + b*KK + t] = v;
  }
}

extern "C" void kernel_launch(void* const* d_in, const int* in_sizes, int n_in,
                              void* d_out, int out_size, void* d_ws, size_t ws_size,
                              hipStream_t stream){
  const float* x    = (const float*)d_in[0];
  const int*   ei   = (const int*)d_in[1];
  const float* ew   = (const float*)d_in[2];
  const float* tgt  = (const float*)d_in[3];
  const float* Wk   = (const float*)d_in[5];
  const float* W1   = (const float*)d_in[6];
  const float* W2   = (const float*)d_in[7];
  const float* W3   = (const float*)d_in[8];
  const float* linW = (const float*)d_in[9];
  float* out = (float*)d_out;

  // workspace layout (floats); total ~27 MB
  float* wf    = (float*)d_ws;
  float* A_g   = wf;                   // 262144
  float* M_g   = A_g + 262144;
  float* S_g   = M_g + 262144;
  float* xq    = S_g + 262144;         // 524288
  float* xq2   = xq + 524288;
  float* aggb  = xq2 + 524288;
  float* xc    = aggb + 524288;
  float* a_buf = xc + 524288;          // 2 x 524288
  float* h1    = a_buf + 1048576;      // 2 x 1048576
  float* h2    = h1 + 2097152;         // 2 x 524288 (also reused for y=agg@linW)
  float* logit = h2 + 1048576;         // 2 x 4096
  float* fb    = logit + 8192;
  float* gb    = fb + 8192;
  float* score = gb + 8192;            // 4096
  int*   perm_int = (int*)(score + 4096);
  int*   pidx     = perm_int + NKOUT;

  float* outX  = out;                          // 3328 x 128
  float* outA2 = out + 425984;                 // 3328 x 3328
  float* outB  = out + 425984 + 11075584;      // 3328
  float* outP  = outB + NKOUT;                 // 3328

  // 1. zero A2 region (off-blocks must be exactly 0; d_out is poisoned pre-launch)
  k_zero4<<<dim3(10816), dim3(256), 0, stream>>>((float4*)outA2, 2768896);
  // 2. dense per-batch normalized adjacency + multiplicity
  k_build<<<dim3(64), dim3(256), 0, stream>>>(ei, ew, A_g, M_g);
  // 3. x_q = hop(hop(x))
  k_hop2<<<dim3(64), dim3(256), 0, stream>>>(A_g, x, xq);
  // 4. attention pair f (kv=x; q: z0=x_q, z1=target)
  k_gemm<<<dim3(2,64,2), dim3(256), 0, stream>>>(x, Wk, a_buf, 128, 128, 0L, 16384L, 524288L, 0);
  k_gemm_h<<<dim3(4,64,2), dim3(256), 0, stream>>>(a_buf, xq, tgt, W1, h1);
  k_gemm<<<dim3(2,64,2), dim3(256), 0, stream>>>(h1, W2, h2, 256, 128, 1048576L, 32768L, 524288L, 1);
  k_w3<<<dim3(1024,1,2), dim3(256), 0, stream>>>(h2, W3, logit);
  k_softmax<<<dim3(64,1,2), dim3(64), 0, stream>>>(logit, fb);
  // 5. edge softmax -> S, agg
  k_edge<<<dim3(64), dim3(256), 0, stream>>>(M_g, fb, x, S_g, aggb);
  // 6. y = agg @ lin_W (2 heads), x_c
  k_gemm<<<dim3(2,64,2), dim3(256), 0, stream>>>(aggb, linW, h2, 128, 128, 0L, 16384L, 524288L, 0);
  k_xc<<<dim3(2048), dim3(256), 0, stream>>>(x, h2, xc);
  // 7. x_q2 = hop(hop(x_c))
  k_hop2<<<dim3(64), dim3(256), 0, stream>>>(A_g, xc, xq2);
  // 8. attention pair g (kv=x_c; q: z0=x_q2, z1=target)
  k_gemm<<<dim3(2,64,2), dim3(256), 0, stream>>>(xc, Wk + 2*16384, a_buf, 128, 128, 0L, 16384L, 524288L, 0);
  k_gemm_h<<<dim3(4,64,2), dim3(256), 0, stream>>>(a_buf, xq2, tgt, W1 + 2*131072, h1);
  k_gemm<<<dim3(2,64,2), dim3(256), 0, stream>>>(h1, W2 + 2*32768, h2, 256, 128, 1048576L, 32768L, 524288L, 1);
  k_w3<<<dim3(1024,1,2), dim3(256), 0, stream>>>(h2, W3 + 2*128, logit);
  k_softmax<<<dim3(64,1,2), dim3(64), 0, stream>>>(logit, gb);
  // 9. cluster score, top-k, gather outputs
  k_score<<<dim3(64), dim3(64), 0, stream>>>(gb, score);
  k_topk<<<dim3(64), dim3(64), 0, stream>>>(score, perm_int, pidx, outB, outP);
  k_xout<<<dim3(1664), dim3(256), 0, stream>>>(x, score, perm_int, outX);
  // 10. per-batch 52x52 blocks of A2
  k_A2<<<dim3(64), dim3(256), 0, stream>>>(A_g, S_g, pidx, outA2);
}

// Round 2
// 332.947 us; speedup vs baseline: 1.4757x; 1.4757x over previous
//
#include <hip/hip_runtime.h>

// Problem constants (B=64 batches, n=64 nodes/batch, H=128, epg=2048 edges/batch)
#define NB 64
#define NPB 64
#define HD 128
#define EPB 2048
#define NNODE 4096     // NB*NPB
#define KK 52          // ceil(0.8*64)
#define NKOUT 3328     // NB*KK
#define NEG 0.01f

__device__ __forceinline__ float lrelu(float v){ return v > 0.f ? v : NEG*v; }

// ---------------- zero-fill (A2 off-block region) ----------------
__global__ void k_zero4(float4* __restrict__ p, int n4){
  int i = blockIdx.x*256 + threadIdx.x;
  if (i < n4) p[i] = make_float4(0.f,0.f,0.f,0.f);
}

// ---------------- build dense per-batch A (normalized) + multiplicity M ----------------
__global__ __launch_bounds__(256) void k_build(const int* __restrict__ ei, const float* __restrict__ w,
                                               float* __restrict__ A_g, float* __restrict__ M_g){
  __shared__ float Ws[4096];
  __shared__ float Mc[4096];
  __shared__ float dv[64];
  int b = blockIdx.x, tid = threadIdx.x;
  for (int i = tid; i < 4096; i += 256){ Ws[i] = 0.f; Mc[i] = 0.f; }
  __syncthreads();
  const int* r0 = ei + b*EPB;
  const int* c0 = ei + NB*EPB + b*EPB;
  const float* w0 = w + b*EPB;
  int base = b*NPB;
  for (int e = tid; e < EPB; e += 256){
    int r = r0[e] - base, c = c0[e] - base;
    atomicAdd(&Ws[r*64 + c], w0[e]);
    atomicAdd(&Mc[r*64 + c], 1.f);
  }
  if (tid < 64){ atomicAdd(&Ws[tid*64 + tid], 1.f); atomicAdd(&Mc[tid*64 + tid], 1.f); }
  __syncthreads();
  if (tid < 64){
    float d = 0.f;
    for (int r = 0; r < 64; r++) d += Ws[r*64 + tid];   // deg over col
    dv[tid] = d > 0.f ? rsqrtf(fmaxf(d, 1e-12f)) : 0.f;
  }
  __syncthreads();
  for (int i = tid; i < 4096; i += 256){
    int r = i >> 6, c = i & 63;
    A_g[b*4096 + i] = dv[r]*Ws[i]*dv[c];
    M_g[b*4096 + i] = Mc[i];
  }
}

// ---------------- double hop: out = A^T (A^T v), per-batch, f-split over blockIdx.y ----------------
// grid (64, 2); block handles batch b, features [f0, f0+64). 4x4 register microtile per thread.
__global__ __launch_bounds__(256) void k_hop2(const float* __restrict__ A_g, const float* __restrict__ v_in,
                                              float* __restrict__ v_out){
  __shared__ __align__(16) float A[4096];   // A[r][c]
  __shared__ __align__(16) float V[4096];   // V[r][f-f0]
  __shared__ __align__(16) float T[4096];   // intermediate [c][f-f0]
  int b = blockIdx.x, f0 = blockIdx.y*64, tid = threadIdx.x;
  for (int i = tid*4; i < 4096; i += 1024)
    *(float4*)&A[i] = *(const float4*)(A_g + b*4096 + i);
  for (int i = tid*4; i < 4096; i += 1024){
    int r = i >> 6, j = i & 63;
    *(float4*)&V[i] = *(const float4*)(v_in + (size_t)b*8192 + r*128 + f0 + j);
  }
  __syncthreads();
  int tc = (tid & 15)*4, tf = (tid >> 4)*4;
  float acc[4][4];
  #pragma unroll
  for (int i = 0; i < 4; i++)
    #pragma unroll
    for (int j = 0; j < 4; j++) acc[i][j] = 0.f;
  // hop 1: T[c][f] = sum_r A[r][c]*V[r][f]
  for (int r = 0; r < 64; r++){
    float4 a4 = *(const float4*)&A[r*64 + tc];
    float4 v4 = *(const float4*)&V[r*64 + tf];
    float a_[4] = {a4.x,a4.y,a4.z,a4.w};
    float v_[4] = {v4.x,v4.y,v4.z,v4.w};
    #pragma unroll
    for (int ci = 0; ci < 4; ci++)
      #pragma unroll
      for (int fj = 0; fj < 4; fj++) acc[ci][fj] += a_[ci]*v_[fj];
  }
  #pragma unroll
  for (int ci = 0; ci < 4; ci++)
    *(float4*)&T[(tc+ci)*64 + tf] = make_float4(acc[ci][0], acc[ci][1], acc[ci][2], acc[ci][3]);
  __syncthreads();
  #pragma unroll
  for (int i = 0; i < 4; i++)
    #pragma unroll
    for (int j = 0; j < 4; j++) acc[i][j] = 0.f;
  // hop 2: out[c][f] = sum_r A[r][c]*T[r][f]
  for (int r = 0; r < 64; r++){
    float4 a4 = *(const float4*)&A[r*64 + tc];
    float4 t4 = *(const float4*)&T[r*64 + tf];
    float a_[4] = {a4.x,a4.y,a4.z,a4.w};
    float t_[4] = {t4.x,t4.y,t4.z,t4.w};
    #pragma unroll
    for (int ci = 0; ci < 4; ci++)
      #pragma unroll
      for (int fj = 0; fj < 4; fj++) acc[ci][fj] += a_[ci]*t_[fj];
  }
  #pragma unroll
  for (int ci = 0; ci < 4; ci++)
    *(float4*)(v_out + (size_t)b*8192 + (tc+ci)*128 + f0 + tf) =
      make_float4(acc[ci][0], acc[ci][1], acc[ci][2], acc[ci][3]);
}

// ---------------- generic fp32 GEMM: C = act(A @ W), 64x64 tiles, z-batched ----------------
__global__ __launch_bounds__(256) void k_gemm(const float* __restrict__ A, const float* __restrict__ W,
                                              float* __restrict__ C, int K, int M,
                                              long az, long wz, long cz, int leaky){
  int z = blockIdx.z;
  A += (size_t)z*az; W += (size_t)z*wz; C += (size_t)z*cz;
  __shared__ __align__(16) float As[16][68];
  __shared__ __align__(16) float Bs[16][68];
  int tid = threadIdx.x, tx = tid & 15, ty = tid >> 4;
  int i0 = blockIdx.y*64, j0 = blockIdx.x*64;
  float acc[4][4] = {};
  for (int k0 = 0; k0 < K; k0 += 16){
    int r = tid >> 2, c4 = (tid & 3)*4;
    float4 av = *(const float4*)(A + (size_t)(i0 + r)*K + k0 + c4);
    As[c4+0][r] = av.x; As[c4+1][r] = av.y; As[c4+2][r] = av.z; As[c4+3][r] = av.w;
    int wr = tid >> 4, wc4 = (tid & 15)*4;
    *(float4*)&Bs[wr][wc4] = *(const float4*)(W + (size_t)(k0 + wr)*M + j0 + wc4);
    __syncthreads();
    #pragma unroll
    for (int k = 0; k < 16; k++){
      float4 a4 = *(const float4*)&As[k][ty*4];
      float4 b4 = *(const float4*)&Bs[k][tx*4];
      float a_[4] = {a4.x, a4.y, a4.z, a4.w};
      float b_[4] = {b4.x, b4.y, b4.z, b4.w};
      #pragma unroll
      for (int ii = 0; ii < 4; ii++)
        #pragma unroll
        for (int jj = 0; jj < 4; jj++)
          acc[ii][jj] += a_[ii]*b_[jj];
    }
    __syncthreads();
  }
  #pragma unroll
  for (int ii = 0; ii < 4; ii++){
    int gi = i0 + ty*4 + ii;
    float4 o;
    o.x = acc[ii][0]; o.y = acc[ii][1]; o.z = acc[ii][2]; o.w = acc[ii][3];
    if (leaky){ o.x = lrelu(o.x); o.y = lrelu(o.y); o.z = lrelu(o.z); o.w = lrelu(o.w); }
    *(float4*)(C + (size_t)gi*M + j0 + tx*4) = o;
  }
}

// ---------------- W1 GEMM with h=[a,q,a-q,a*q] synthesized in staging (K=512, M=256) ----------------
__global__ __launch_bounds__(256) void k_gemm_h(const float* __restrict__ a_buf, const float* __restrict__ q0,
                                                const float* __restrict__ tgt, const float* __restrict__ W1,
                                                float* __restrict__ C){
  int z = blockIdx.z;
  const float* A = a_buf + (size_t)z*NNODE*HD;
  const float* W = W1 + (size_t)z*512*256;
  float* Cz = C + (size_t)z*NNODE*256;
  __shared__ __align__(16) float As[16][68];
  __shared__ __align__(16) float Bs[16][68];
  int tid = threadIdx.x, tx = tid & 15, ty = tid >> 4;
  int i0 = blockIdx.y*64, j0 = blockIdx.x*64;
  float acc[4][4] = {};
  for (int k0 = 0; k0 < 512; k0 += 16){
    int seg = k0 >> 7, kk = k0 & 127;
    int r = tid >> 2, c4 = (tid & 3)*4;
    int gi = i0 + r;
    float4 hv;
    if (seg == 0){
      hv = *(const float4*)(A + (size_t)gi*HD + kk + c4);
    } else if (seg == 1){
      hv = (z == 0) ? *(const float4*)(q0 + (size_t)gi*HD + kk + c4)
                    : *(const float4*)(tgt + (size_t)(gi >> 6)*HD + kk + c4);
    } else {
      float4 avv = *(const float4*)(A + (size_t)gi*HD + kk + c4);
      float4 qv = (z == 0) ? *(const float4*)(q0 + (size_t)gi*HD + kk + c4)
                           : *(const float4*)(tgt + (size_t)(gi >> 6)*HD + kk + c4);
      if (seg == 2){ hv.x = avv.x - qv.x; hv.y = avv.y - qv.y; hv.z = avv.z - qv.z; hv.w = avv.w - qv.w; }
      else         { hv.x = avv.x * qv.x; hv.y = avv.y * qv.y; hv.z = avv.z * qv.z; hv.w = avv.w * qv.w; }
    }
    As[c4+0][r] = hv.x; As[c4+1][r] = hv.y; As[c4+2][r] = hv.z; As[c4+3][r] = hv.w;
    int wr = tid >> 4, wc4 = (tid & 15)*4;
    *(float4*)&Bs[wr][wc4] = *(const float4*)(W + (size_t)(k0 + wr)*256 + j0 + wc4);
    __syncthreads();
    #pragma unroll
    for (int k = 0; k < 16; k++){
      float4 a4 = *(const float4*)&As[k][ty*4];
      float4 b4 = *(const float4*)&Bs[k][tx*4];
      float a_[4] = {a4.x, a4.y, a4.z, a4.w};
      float b_[4] = {b4.x, b4.y, b4.z, b4.w};
      #pragma unroll
      for (int ii = 0; ii < 4; ii++)
        #pragma unroll
        for (int jj = 0; jj < 4; jj++)
          acc[ii][jj] += a_[ii]*b_[jj];
    }
    __syncthreads();
  }
  #pragma unroll
  for (int ii = 0; ii < 4; ii++){
    int gi = i0 + ty*4 + ii;
    float4 o;
    o.x = lrelu(acc[ii][0]); o.y = lrelu(acc[ii][1]); o.z = lrelu(acc[ii][2]); o.w = lrelu(acc[ii][3]);
    *(float4*)(Cz + (size_t)gi*256 + j0 + tx*4) = o;
  }
}

// ---------------- final MLP layer: logit = leaky(h2 . W3), one wave per row ----------------
__global__ __launch_bounds__(256) void k_w3(const float* __restrict__ h2, const float* __restrict__ W3,
                                            float* __restrict__ logit){
  int z = blockIdx.z;
  int wave = threadIdx.x >> 6, lane = threadIdx.x & 63;
  int row = blockIdx.x*4 + wave;
  const float* h = h2 + ((size_t)z*NNODE + row)*HD;
  const float* w = W3 + (size_t)z*HD;
  float v = h[lane]*w[lane] + h[lane + 64]*w[lane + 64];
  #pragma unroll
  for (int off = 32; off; off >>= 1) v += __shfl_down(v, off);
  if (lane == 0) logit[z*NNODE + row] = lrelu(v);
}

// ---------------- per-batch softmax over 64 logits ----------------
__global__ void k_softmax(const float* __restrict__ logit, float* __restrict__ f){
  int z = blockIdx.z, b = blockIdx.x, lane = threadIdx.x;
  float l = logit[z*NNODE + b*64 + lane];
  float m = l;
  #pragma unroll
  for (int off = 32; off; off >>= 1) m = fmaxf(m, __shfl_xor(m, off));
  float e = expf(l - m);
  float s = e;
  #pragma unroll
  for (int off = 32; off; off >>= 1) s += __shfl_xor(s, off);
  f[z*NNODE + b*64 + lane] = e/s;
}

// ---------------- cluster score: softmax over batch of (g1+g2) ----------------
__global__ void k_score(const float* __restrict__ g, float* __restrict__ score){
  int b = blockIdx.x, lane = threadIdx.x;
  float l = g[b*64 + lane] + g[NNODE + b*64 + lane];
  float m = l;
  #pragma unroll
  for (int off = 32; off; off >>= 1) m = fmaxf(m, __shfl_xor(m, off));
  float e = expf(l - m);
  float s = e;
  #pragma unroll
  for (int off = 32; off; off >>= 1) s += __shfl_xor(s, off);
  score[b*64 + lane] = e/s;
}

// ---------------- edge softmax (multiplicity-weighted) + S + agg ----------------
__global__ __launch_bounds__(256) void k_edge(const float* __restrict__ M_g, const float* __restrict__ fb,
                                              const float* __restrict__ x, float* __restrict__ S_g,
                                              float* __restrict__ agg){
  __shared__ __align__(16) float Mc[4096];   // in: multiplicity, out (in-place): Ew = M*E
  __shared__ __align__(16) float xb[8192];
  __shared__ float f1s[64], f2s[64];
  int b = blockIdx.x, tid = threadIdx.x;
  for (int i = tid; i < 4096; i += 256) Mc[i] = M_g[b*4096 + i];
  for (int i = tid*4; i < 8192; i += 1024)
    *(float4*)&xb[i] = *(const float4*)(x + (size_t)b*8192 + i);
  if (tid < 64) f1s[tid] = fb[b*64 + tid];
  else if (tid < 128) f2s[tid - 64] = fb[NNODE + b*64 + (tid - 64)];
  __syncthreads();
  int c = tid >> 2, sub = tid & 3;   // 4 lanes per column
  float m = -1e30f;
  for (int r = sub; r < 64; r += 4)
    if (Mc[r*64 + c] > 0.f) m = fmaxf(m, lrelu(f1s[c] + f2s[r]));
  m = fmaxf(m, __shfl_xor(m, 1));
  m = fmaxf(m, __shfl_xor(m, 2));
  float s = 0.f;
  for (int r = sub; r < 64; r += 4){
    float mc = Mc[r*64 + c];
    if (mc > 0.f) s += mc*expf(lrelu(f1s[c] + f2s[r]) - m);
  }
  s += __shfl_xor(s, 1);
  s += __shfl_xor(s, 2);
  for (int r = sub; r < 64; r += 4){
    float mc = Mc[r*64 + c];
    float v = 0.f;
    if (mc > 0.f) v = mc*expf(lrelu(f1s[c] + f2s[r]) - m)/s;
    Mc[r*64 + c] = v;
  }
  __syncthreads();
  for (int i = tid; i < 4096; i += 256) S_g[b*4096 + i] = Mc[i];
  // agg[c][f] = sum_r Ew[r][c]*x[r][f] — 4c x 8f register microtile
  int tc = (tid & 15)*4, tf = (tid >> 4)*8;
  float acc[4][8];
  #pragma unroll
  for (int i = 0; i < 4; i++)
    #pragma unroll
    for (int j = 0; j < 8; j++) acc[i][j] = 0.f;
  for (int r = 0; r < 64; r++){
    float4 e4 = *(const float4*)&Mc[r*64 + tc];
    float4 x0 = *(const float4*)&xb[r*128 + tf];
    float4 x1 = *(const float4*)&xb[r*128 + tf + 4];
    float e_[4] = {e4.x,e4.y,e4.z,e4.w};
    float x_[8] = {x0.x,x0.y,x0.z,x0.w,x1.x,x1.y,x1.z,x1.w};
    #pragma unroll
    for (int ci = 0; ci < 4; ci++)
      #pragma unroll
      for (int fj = 0; fj < 8; fj++) acc[ci][fj] += e_[ci]*x_[fj];
  }
  #pragma unroll
  for (int ci = 0; ci < 4; ci++){
    *(float4*)(agg + (size_t)b*8192 + (tc+ci)*128 + tf)     = make_float4(acc[ci][0],acc[ci][1],acc[ci][2],acc[ci][3]);
    *(float4*)(agg + (size_t)b*8192 + (tc+ci)*128 + tf + 4) = make_float4(acc[ci][4],acc[ci][5],acc[ci][6],acc[ci][7]);
  }
}

// ---------------- x_c = 0.5*(leaky(x+y0)+leaky(x+y1)) ----------------
__global__ void k_xc(const float* __restrict__ x, const float* __restrict__ y, float* __restrict__ xc){
  int i = blockIdx.x*256 + threadIdx.x;
  float xv = x[i];
  xc[i] = 0.5f*(lrelu(xv + y[i]) + lrelu(xv + y[NNODE*HD + i]));
}

// ---------------- exact top-52 per batch, descending, lowest-index tie-break ----------------
__global__ void k_topk(const float* __restrict__ score, int* __restrict__ perm_int, int* __restrict__ pidx,
                       float* __restrict__ out_batch, float* __restrict__ out_perm){
  int b = blockIdx.x, lane = threadIdx.x;
  float s = score[b*64 + lane];
  for (int t = 0; t < KK; t++){
    float v = s; int idx = lane;
    #pragma unroll
    for (int off = 32; off; off >>= 1){
      float ov = __shfl_xor(v, off); int oi = __shfl_xor(idx, off);
      if (ov > v || (ov == v && oi < idx)){ v = ov; idx = oi; }
    }
    if (lane == 0){
      perm_int[b*KK + t] = b*64 + idx;
      pidx[b*KK + t] = idx;
      out_batch[b*KK + t] = (float)b;
      out_perm[b*KK + t] = (float)(b*64 + idx);
    }
    if (lane == idx) s = -1e30f;
  }
}

// ---------------- x_out = x[perm]*score[perm] ----------------
__global__ void k_xout(const float* __restrict__ x, const float* __restrict__ score,
                       const int* __restrict__ perm_int, float* __restrict__ out){
  int g = blockIdx.x*256 + threadIdx.x;   // 425984 total
  int j = g >> 7, f = g & 127;
  int p = perm_int[j];
  out[g] = x[p*128 + f]*score[p];
}

// ---------------- per-batch A2 block: S_p^T (A S_p), diag=1 ----------------
__global__ __launch_bounds__(256) void k_A2(const float* __restrict__ A_g, const float* __restrict__ S_g,
                                            const int* __restrict__ pidx, float* __restrict__ outA2){
  __shared__ __align__(16) float At[64*68];  // At[k][i] = A[i][k], pad 68
  __shared__ __align__(16) float Sp[64*56];  // Sp[k][t] = S[k][pc[t]], pad 56 (t>=52 zero)
  __shared__ __align__(16) float T[64*56];   // T[i][t]
  __shared__ int pc[KK];
  int b = blockIdx.x, tid = threadIdx.x;
  if (tid < KK) pc[tid] = pidx[b*KK + tid];
  __syncthreads();
  // load A transposed (coalesced global read; LDS write has benign one-time conflicts)
  for (int idx = tid; idx < 4096; idx += 256){
    int i = idx >> 6, k = idx & 63;
    At[k*68 + i] = A_g[b*4096 + idx];
  }
  // gather Sp columns
  for (int idx = tid; idx < 4096; idx += 256){
    int k = idx >> 6, t = idx & 63;
    if (t < 56) Sp[k*56 + t] = (t < KK) ? S_g[b*4096 + k*64 + pc[t]] : 0.f;
  }
  __syncthreads();
  // stage 1: T[i][t] = sum_k A[i][k]*Sp[k][t]; 16 i-groups x 14 t-groups
  if (tid < 224){
    int i0 = (tid/14)*4, t0 = (tid % 14)*4;
    float acc[4][4];
    #pragma unroll
    for (int a = 0; a < 4; a++)
      #pragma unroll
      for (int c = 0; c < 4; c++) acc[a][c] = 0.f;
    for (int k = 0; k < 64; k++){
      float4 a4 = *(const float4*)&At[k*68 + i0];
      float4 s4 = *(const float4*)&Sp[k*56 + t0];
      float a_[4] = {a4.x,a4.y,a4.z,a4.w};
      float s_[4] = {s4.x,s4.y,s4.z,s4.w};
      #pragma unroll
      for (int ii = 0; ii < 4; ii++)
        #pragma unroll
        for (int tt = 0; tt < 4; tt++) acc[ii][tt] += a_[ii]*s_[tt];
    }
    #pragma unroll
    for (int ii = 0; ii < 4; ii++)
      *(float4*)&T[(i0+ii)*56 + t0] = make_float4(acc[ii][0],acc[ii][1],acc[ii][2],acc[ii][3]);
  }
  __syncthreads();
  // stage 2: out[a][t] = sum_i Sp[i][a]*T[i][t]; 13 a-groups x 13 t-groups
  if (tid < 169){
    int a0 = (tid/13)*4, t0 = (tid % 13)*4;
    float acc[4][4];
    #pragma unroll
    for (int a = 0; a < 4; a++)
      #pragma unroll
      for (int c = 0; c < 4; c++) acc[a][c] = 0.f;
    for (int i = 0; i < 64; i++){
      float4 s4 = *(const float4*)&Sp[i*56 + a0];
      float4 t4 = *(const float4*)&T[i*56 + t0];
      float s_[4] = {s4.x,s4.y,s4.z,s4.w};
      float t_[4] = {t4.x,t4.y,t4.z,t4.w};
      #pragma unroll
      for (int aa = 0; aa < 4; aa++)
        #pragma unroll
        for (int tt = 0; tt < 4; tt++) acc[aa][tt] += s_[aa]*t_[tt];
    }
    #pragma unroll
    for (int aa = 0; aa < 4; aa++)
      #pragma unroll
      for (int tt = 0; tt < 4; tt++){
        int a = a0 + aa, t = t0 + tt;
        float v = (a == t) ? 1.f : acc[aa][tt];
        outA2[(size_t)(b*KK + a)*NKOUT + b*KK + t] = v;
      }
  }
}

extern "C" void kernel_launch(void* const* d_in, const int* in_sizes, int n_in,
                              void* d_out, int out_size, void* d_ws, size_t ws_size,
                              hipStream_t stream){
  const float* x    = (const float*)d_in[0];
  const int*   ei   = (const int*)d_in[1];
  const float* ew   = (const float*)d_in[2];
  const float* tgt  = (const float*)d_in[3];
  const float* Wk   = (const float*)d_in[5];
  const float* W1   = (const float*)d_in[6];
  const float* W2   = (const float*)d_in[7];
  const float* W3   = (const float*)d_in[8];
  const float* linW = (const float*)d_in[9];
  float* out = (float*)d_out;

  // workspace layout (floats); total ~27 MB
  float* wf    = (float*)d_ws;
  float* A_g   = wf;                   // 262144
  float* M_g   = A_g + 262144;
  float* S_g   = M_g + 262144;
  float* xq    = S_g + 262144;         // 524288
  float* xq2   = xq + 524288;
  float* aggb  = xq2 + 524288;
  float* xc    = aggb + 524288;
  float* a_buf = xc + 524288;          // 2 x 524288
  float* h1    = a_buf + 1048576;      // 2 x 1048576
  float* h2    = h1 + 2097152;         // 2 x 524288 (also reused for y=agg@linW)
  float* logit = h2 + 1048576;         // 2 x 4096
  float* fb    = logit + 8192;
  float* gb    = fb + 8192;
  float* score = gb + 8192;            // 4096
  int*   perm_int = (int*)(score + 4096);
  int*   pidx     = perm_int + NKOUT;

  float* outX  = out;                          // 3328 x 128
  float* outA2 = out + 425984;                 // 3328 x 3328
  float* outB  = out + 425984 + 11075584;      // 3328
  float* outP  = outB + NKOUT;                 // 3328

  // 1. zero A2 region (off-blocks must be exactly 0; d_out is poisoned pre-launch)
  k_zero4<<<dim3(10816), dim3(256), 0, stream>>>((float4*)outA2, 2768896);
  // 2. dense per-batch normalized adjacency + multiplicity
  k_build<<<dim3(64), dim3(256), 0, stream>>>(ei, ew, A_g, M_g);
  // 3. x_q = hop(hop(x))
  k_hop2<<<dim3(64,2), dim3(256), 0, stream>>>(A_g, x, xq);
  // 4. attention pair f (kv=x; q: z0=x_q, z1=target)
  k_gemm<<<dim3(2,64,2), dim3(256), 0, stream>>>(x, Wk, a_buf, 128, 128, 0L, 16384L, 524288L, 0);
  k_gemm_h<<<dim3(4,64,2), dim3(256), 0, stream>>>(a_buf, xq, tgt, W1, h1);
  k_gemm<<<dim3(2,64,2), dim3(256), 0, stream>>>(h1, W2, h2, 256, 128, 1048576L, 32768L, 524288L, 1);
  k_w3<<<dim3(1024,1,2), dim3(256), 0, stream>>>(h2, W3, logit);
  k_softmax<<<dim3(64,1,2), dim3(64), 0, stream>>>(logit, fb);
  // 5. edge softmax -> S, agg
  k_edge<<<dim3(64), dim3(256), 0, stream>>>(M_g, fb, x, S_g, aggb);
  // 6. y = agg @ lin_W (2 heads), x_c
  k_gemm<<<dim3(2,64,2), dim3(256), 0, stream>>>(aggb, linW, h2, 128, 128, 0L, 16384L, 524288L, 0);
  k_xc<<<dim3(2048), dim3(256), 0, stream>>>(x, h2, xc);
  // 7. x_q2 = hop(hop(x_c))
  k_hop2<<<dim3(64,2), dim3(256), 0, stream>>>(A_g, xc, xq2);
  // 8. attention pair g (kv=x_c; q: z0=x_q2, z1=target)
  k_gemm<<<dim3(2,64,2), dim3(256), 0, stream>>>(xc, Wk + 2*16384, a_buf, 128, 128, 0L, 16384L, 524288L, 0);
  k_gemm_h<<<dim3(4,64,2), dim3(256), 0, stream>>>(a_buf, xq2, tgt, W1 + 2*131072, h1);
  k_gemm<<<dim3(2,64,2), dim3(256), 0, stream>>>(h1, W2 + 2*32768, h2, 256, 128, 1048576L, 32768L, 524288L, 1);
  k_w3<<<dim3(1024,1,2), dim3(256), 0, stream>>>(h2, W3 + 2*128, logit);
  k_softmax<<<dim3(64,1,2), dim3(64), 0, stream>>>(logit, gb);
  // 9. cluster score, top-k, gather outputs
  k_score<<<dim3(64), dim3(64), 0, stream>>>(gb, score);
  k_topk<<<dim3(64), dim3(64), 0, stream>>>(score, perm_int, pidx, outB, outP);
  k_xout<<<dim3(1664), dim3(256), 0, stream>>>(x, score, perm_int, outX);
  // 10. per-batch 52x52 blocks of A2
  k_A2<<<dim3(64), dim3(256), 0, stream>>>(A_g, S_g, pidx, outA2);
}

// Round 3
// 313.834 us; speedup vs baseline: 1.5656x; 1.0609x over previous
//
#include <hip/hip_runtime.h>

// Problem constants (B=64 batches, n=64 nodes/batch, H=128, epg=2048 edges/batch)
#define NB 64
#define NPB 64
#define HD 128
#define EPB 2048
#define NNODE 4096     // NB*NPB
#define KK 52          // ceil(0.8*64)
#define NKOUT 3328     // NB*KK
#define NEG 0.01f

__device__ __forceinline__ float lrelu(float v){ return v > 0.f ? v : NEG*v; }
__device__ __forceinline__ float4 f4add(float4 a, float4 b){ return make_float4(a.x+b.x,a.y+b.y,a.z+b.z,a.w+b.w); }
__device__ __forceinline__ float4 f4sub(float4 a, float4 b){ return make_float4(a.x-b.x,a.y-b.y,a.z-b.z,a.w-b.w); }
__device__ __forceinline__ float4 f4mul(float4 a, float4 b){ return make_float4(a.x*b.x,a.y*b.y,a.z*b.z,a.w*b.w); }

// ---------------- zero-fill (A2 off-block region) ----------------
__global__ void k_zero4(float4* __restrict__ p, int n4){
  int i = blockIdx.x*256 + threadIdx.x;
  if (i < n4) p[i] = make_float4(0.f,0.f,0.f,0.f);
}

// ---------------- build dense per-batch A (normalized) + multiplicity M ----------------
__global__ __launch_bounds__(256) void k_build(const int* __restrict__ ei, const float* __restrict__ w,
                                               float* __restrict__ A_g, float* __restrict__ M_g){
  __shared__ float Ws[4096];
  __shared__ float Mc[4096];
  __shared__ float dv[64];
  int b = blockIdx.x, tid = threadIdx.x;
  for (int i = tid; i < 4096; i += 256){ Ws[i] = 0.f; Mc[i] = 0.f; }
  __syncthreads();
  const int* r0 = ei + b*EPB;
  const int* c0 = ei + NB*EPB + b*EPB;
  const float* w0 = w + b*EPB;
  int base = b*NPB;
  for (int e = tid; e < EPB; e += 256){
    int r = r0[e] - base, c = c0[e] - base;
    atomicAdd(&Ws[r*64 + c], w0[e]);
    atomicAdd(&Mc[r*64 + c], 1.f);
  }
  if (tid < 64){ atomicAdd(&Ws[tid*64 + tid], 1.f); atomicAdd(&Mc[tid*64 + tid], 1.f); }
  __syncthreads();
  if (tid < 64){
    float d = 0.f;
    for (int r = 0; r < 64; r++) d += Ws[r*64 + tid];   // deg over col
    dv[tid] = d > 0.f ? rsqrtf(fmaxf(d, 1e-12f)) : 0.f;
  }
  __syncthreads();
  for (int i = tid; i < 4096; i += 256){
    int r = i >> 6, c = i & 63;
    A_g[b*4096 + i] = dv[r]*Ws[i]*dv[c];
    M_g[b*4096 + i] = Mc[i];
  }
}

// ---------------- double hop: out = A^T (A^T v), per-batch, f-split over blockIdx.y ----------------
__global__ __launch_bounds__(256) void k_hop2(const float* __restrict__ A_g, const float* __restrict__ v_in,
                                              float* __restrict__ v_out){
  __shared__ __align__(16) float A[4096];   // A[r][c]
  __shared__ __align__(16) float V[4096];   // V[r][f-f0]
  __shared__ __align__(16) float T[4096];   // intermediate [c][f-f0]
  int b = blockIdx.x, f0 = blockIdx.y*64, tid = threadIdx.x;
  for (int i = tid*4; i < 4096; i += 1024)
    *(float4*)&A[i] = *(const float4*)(A_g + b*4096 + i);
  for (int i = tid*4; i < 4096; i += 1024){
    int r = i >> 6, j = i & 63;
    *(float4*)&V[i] = *(const float4*)(v_in + (size_t)b*8192 + r*128 + f0 + j);
  }
  __syncthreads();
  int tc = (tid & 15)*4, tf = (tid >> 4)*4;
  float acc[4][4];
  #pragma unroll
  for (int i = 0; i < 4; i++)
    #pragma unroll
    for (int j = 0; j < 4; j++) acc[i][j] = 0.f;
  for (int r = 0; r < 64; r++){
    float4 a4 = *(const float4*)&A[r*64 + tc];
    float4 v4 = *(const float4*)&V[r*64 + tf];
    float a_[4] = {a4.x,a4.y,a4.z,a4.w};
    float v_[4] = {v4.x,v4.y,v4.z,v4.w};
    #pragma unroll
    for (int ci = 0; ci < 4; ci++)
      #pragma unroll
      for (int fj = 0; fj < 4; fj++) acc[ci][fj] += a_[ci]*v_[fj];
  }
  #pragma unroll
  for (int ci = 0; ci < 4; ci++)
    *(float4*)&T[(tc+ci)*64 + tf] = make_float4(acc[ci][0], acc[ci][1], acc[ci][2], acc[ci][3]);
  __syncthreads();
  #pragma unroll
  for (int i = 0; i < 4; i++)
    #pragma unroll
    for (int j = 0; j < 4; j++) acc[i][j] = 0.f;
  for (int r = 0; r < 64; r++){
    float4 a4 = *(const float4*)&A[r*64 + tc];
    float4 t4 = *(const float4*)&T[r*64 + tf];
    float a_[4] = {a4.x,a4.y,a4.z,a4.w};
    float t_[4] = {t4.x,t4.y,t4.z,t4.w};
    #pragma unroll
    for (int ci = 0; ci < 4; ci++)
      #pragma unroll
      for (int fj = 0; fj < 4; fj++) acc[ci][fj] += a_[ci]*t_[fj];
  }
  #pragma unroll
  for (int ci = 0; ci < 4; ci++)
    *(float4*)(v_out + (size_t)b*8192 + (tc+ci)*128 + f0 + tf) =
      make_float4(acc[ci][0], acc[ci][1], acc[ci][2], acc[ci][3]);
}

// ---------------- generic fp32 GEMM: C = act(A @ W), 64x64 tile, BK=32, register prefetch ----------------
__global__ __launch_bounds__(256) void k_gemm(const float* __restrict__ A, const float* __restrict__ W,
                                              float* __restrict__ C, int K, int M,
                                              long az, long wz, long cz, int leaky){
  int z = blockIdx.z;
  A += (size_t)z*az; W += (size_t)z*wz; C += (size_t)z*cz;
  __shared__ __align__(16) float As[32][68];
  __shared__ __align__(16) float Bs[32][68];
  int tid = threadIdx.x, tx = tid & 15, ty = tid >> 4;
  int i0 = blockIdx.y*64, j0 = blockIdx.x*64;
  int ar = tid >> 2, ak = (tid & 3)*4;
  int wr = tid >> 4, wc = (tid & 15)*4;
  const float* Arow = A + (size_t)(i0 + ar)*K;
  float4 pa0 = *(const float4*)(Arow + ak);
  float4 pa1 = *(const float4*)(Arow + ak + 16);
  float4 pw0 = *(const float4*)(W + (size_t)wr*M + j0 + wc);
  float4 pw1 = *(const float4*)(W + (size_t)(wr + 16)*M + j0 + wc);
  float acc[4][4] = {};
  for (int k0 = 0; k0 < K; k0 += 32){
    As[ak+0][ar] = pa0.x; As[ak+1][ar] = pa0.y; As[ak+2][ar] = pa0.z; As[ak+3][ar] = pa0.w;
    As[ak+16][ar] = pa1.x; As[ak+17][ar] = pa1.y; As[ak+18][ar] = pa1.z; As[ak+19][ar] = pa1.w;
    *(float4*)&Bs[wr][wc] = pw0;
    *(float4*)&Bs[wr+16][wc] = pw1;
    __syncthreads();
    if (k0 + 32 < K){
      pa0 = *(const float4*)(Arow + k0 + 32 + ak);
      pa1 = *(const float4*)(Arow + k0 + 48 + ak);
      pw0 = *(const float4*)(W + (size_t)(k0 + 32 + wr)*M + j0 + wc);
      pw1 = *(const float4*)(W + (size_t)(k0 + 48 + wr)*M + j0 + wc);
    }
    #pragma unroll
    for (int k = 0; k < 32; k++){
      float4 a4 = *(const float4*)&As[k][ty*4];
      float4 b4 = *(const float4*)&Bs[k][tx*4];
      float a_[4] = {a4.x, a4.y, a4.z, a4.w};
      float b_[4] = {b4.x, b4.y, b4.z, b4.w};
      #pragma unroll
      for (int ii = 0; ii < 4; ii++)
        #pragma unroll
        for (int jj = 0; jj < 4; jj++)
          acc[ii][jj] += a_[ii]*b_[jj];
    }
    __syncthreads();
  }
  #pragma unroll
  for (int ii = 0; ii < 4; ii++){
    int gi = i0 + ty*4 + ii;
    float4 o;
    o.x = acc[ii][0]; o.y = acc[ii][1]; o.z = acc[ii][2]; o.w = acc[ii][3];
    if (leaky){ o.x = lrelu(o.x); o.y = lrelu(o.y); o.z = lrelu(o.z); o.w = lrelu(o.w); }
    *(float4*)(C + (size_t)gi*M + j0 + tx*4) = o;
  }
}

// ---------------- W1 GEMM, folded: h@W1 = a@(W1a+W1c) + q@(W1b-W1c) + (a*q)@W1d (K=384) ----------------
// z=0: query = q0 (per-node). z=1: query = tgt[batch] broadcast.
__global__ __launch_bounds__(256) void k_gemm_h(const float* __restrict__ a_buf, const float* __restrict__ q0,
                                                const float* __restrict__ tgt, const float* __restrict__ W1,
                                                float* __restrict__ C){
  int z = blockIdx.z;
  const float* Az = a_buf + (size_t)z*NNODE*HD;
  const float* Wz = W1 + (size_t)z*512*256;
  float* Cz = C + (size_t)z*NNODE*256;
  __shared__ __align__(16) float As[32][68];
  __shared__ __align__(16) float Bs[32][68];
  int tid = threadIdx.x, tx = tid & 15, ty = tid >> 4;
  int i0 = blockIdx.y*64, j0 = blockIdx.x*64;
  int ar = tid >> 2, ak = (tid & 3)*4;
  int wr = tid >> 4, wc = (tid & 15)*4;
  int gi = i0 + ar;
  const float* arow = Az + (size_t)gi*HD;
  const float* qrow = (z == 0) ? q0 + (size_t)gi*HD : tgt + (size_t)(gi >> 6)*HD;
  float4 na0, na1, nq0, nq1, nw0, nw1;
  int segp = 0;
  auto prefetch = [&](int k0p){
    int kk = (k0p & 127) + ak;
    segp = k0p >> 7;
    na0 = *(const float4*)(arow + kk);
    na1 = *(const float4*)(arow + kk + 16);
    nq0 = *(const float4*)(qrow + kk);
    nq1 = *(const float4*)(qrow + kk + 16);
    int kr = k0p + wr;
    const float* wp = Wz + (size_t)kr*256 + j0 + wc;
    if (kr < 128){
      nw0 = f4add(*(const float4*)wp,            *(const float4*)(wp + 256*256));
      nw1 = f4add(*(const float4*)(wp + 16*256), *(const float4*)(wp + 272*256));
    } else if (kr < 256){
      nw0 = f4sub(*(const float4*)wp,            *(const float4*)(wp + 128*256));
      nw1 = f4sub(*(const float4*)(wp + 16*256), *(const float4*)(wp + 144*256));
    } else {
      nw0 = *(const float4*)(wp + 128*256);
      nw1 = *(const float4*)(wp + 144*256);
    }
  };
  prefetch(0);
  float acc[4][4] = {};
  for (int k0 = 0; k0 < 384; k0 += 32){
    float4 h0, h1v;
    if (segp == 0){ h0 = na0; h1v = na1; }
    else if (segp == 1){ h0 = nq0; h1v = nq1; }
    else { h0 = f4mul(na0, nq0); h1v = f4mul(na1, nq1); }
    As[ak+0][ar] = h0.x; As[ak+1][ar] = h0.y; As[ak+2][ar] = h0.z; As[ak+3][ar] = h0.w;
    As[ak+16][ar] = h1v.x; As[ak+17][ar] = h1v.y; As[ak+18][ar] = h1v.z; As[ak+19][ar] = h1v.w;
    *(float4*)&Bs[wr][wc] = nw0;
    *(float4*)&Bs[wr+16][wc] = nw1;
    __syncthreads();
    if (k0 + 32 < 384) prefetch(k0 + 32);
    #pragma unroll
    for (int k = 0; k < 32; k++){
      float4 a4 = *(const float4*)&As[k][ty*4];
      float4 b4 = *(const float4*)&Bs[k][tx*4];
      float a_[4] = {a4.x, a4.y, a4.z, a4.w};
      float b_[4] = {b4.x, b4.y, b4.z, b4.w};
      #pragma unroll
      for (int ii = 0; ii < 4; ii++)
        #pragma unroll
        for (int jj = 0; jj < 4; jj++)
          acc[ii][jj] += a_[ii]*b_[jj];
    }
    __syncthreads();
  }
  #pragma unroll
  for (int ii = 0; ii < 4; ii++){
    int go = i0 + ty*4 + ii;
    float4 o;
    o.x = lrelu(acc[ii][0]); o.y = lrelu(acc[ii][1]); o.z = lrelu(acc[ii][2]); o.w = lrelu(acc[ii][3]);
    *(float4*)(Cz + (size_t)go*256 + j0 + tx*4) = o;
  }
}

// ---------------- fused W3 dot + per-batch softmax ----------------
__global__ __launch_bounds__(256) void k_w3sm(const float* __restrict__ h2, const float* __restrict__ W3,
                                              float* __restrict__ outF){
  int b = blockIdx.x, z = blockIdx.z;
  int wave = threadIdx.x >> 6, lane = threadIdx.x & 63;
  __shared__ float lg[64];
  const float* w = W3 + (size_t)z*HD;
  float w0 = w[lane], w1 = w[lane + 64];
  #pragma unroll 4
  for (int i = 0; i < 16; i++){
    int row = wave*16 + i;
    const float* h = h2 + ((size_t)z*NNODE + b*64 + row)*HD;
    float v = h[lane]*w0 + h[lane + 64]*w1;
    #pragma unroll
    for (int off = 32; off; off >>= 1) v += __shfl_down(v, off);
    if (lane == 0) lg[row] = lrelu(v);
  }
  __syncthreads();
  if (threadIdx.x < 64){
    float l = lg[threadIdx.x];
    float m = l;
    #pragma unroll
    for (int off = 32; off; off >>= 1) m = fmaxf(m, __shfl_xor(m, off));
    float e = expf(l - m);
    float s = e;
    #pragma unroll
    for (int off = 32; off; off >>= 1) s += __shfl_xor(s, off);
    outF[z*NNODE + b*64 + threadIdx.x] = e/s;
  }
}

// ---------------- edge softmax (multiplicity-weighted) + S + agg ----------------
__global__ __launch_bounds__(256) void k_edge(const float* __restrict__ M_g, const float* __restrict__ fb,
                                              const float* __restrict__ x, float* __restrict__ S_g,
                                              float* __restrict__ agg){
  __shared__ __align__(16) float Mc[4096];   // in: multiplicity, out (in-place): Ew = M*E
  __shared__ __align__(16) float xb[8192];
  __shared__ float f1s[64], f2s[64];
  int b = blockIdx.x, tid = threadIdx.x;
  for (int i = tid; i < 4096; i += 256) Mc[i] = M_g[b*4096 + i];
  for (int i = tid*4; i < 8192; i += 1024)
    *(float4*)&xb[i] = *(const float4*)(x + (size_t)b*8192 + i);
  if (tid < 64) f1s[tid] = fb[b*64 + tid];
  else if (tid < 128) f2s[tid - 64] = fb[NNODE + b*64 + (tid - 64)];
  __syncthreads();
  int c = tid >> 2, sub = tid & 3;
  float m = -1e30f;
  for (int r = sub; r < 64; r += 4)
    if (Mc[r*64 + c] > 0.f) m = fmaxf(m, lrelu(f1s[c] + f2s[r]));
  m = fmaxf(m, __shfl_xor(m, 1));
  m = fmaxf(m, __shfl_xor(m, 2));
  float s = 0.f;
  for (int r = sub; r < 64; r += 4){
    float mc = Mc[r*64 + c];
    if (mc > 0.f) s += mc*expf(lrelu(f1s[c] + f2s[r]) - m);
  }
  s += __shfl_xor(s, 1);
  s += __shfl_xor(s, 2);
  for (int r = sub; r < 64; r += 4){
    float mc = Mc[r*64 + c];
    float v = 0.f;
    if (mc > 0.f) v = mc*expf(lrelu(f1s[c] + f2s[r]) - m)/s;
    Mc[r*64 + c] = v;
  }
  __syncthreads();
  for (int i = tid; i < 4096; i += 256) S_g[b*4096 + i] = Mc[i];
  int tc = (tid & 15)*4, tf = (tid >> 4)*8;
  float acc[4][8];
  #pragma unroll
  for (int i = 0; i < 4; i++)
    #pragma unroll
    for (int j = 0; j < 8; j++) acc[i][j] = 0.f;
  for (int r = 0; r < 64; r++){
    float4 e4 = *(const float4*)&Mc[r*64 + tc];
    float4 x0 = *(const float4*)&xb[r*128 + tf];
    float4 x1 = *(const float4*)&xb[r*128 + tf + 4];
    float e_[4] = {e4.x,e4.y,e4.z,e4.w};
    float x_[8] = {x0.x,x0.y,x0.z,x0.w,x1.x,x1.y,x1.z,x1.w};
    #pragma unroll
    for (int ci = 0; ci < 4; ci++)
      #pragma unroll
      for (int fj = 0; fj < 8; fj++) acc[ci][fj] += e_[ci]*x_[fj];
  }
  #pragma unroll
  for (int ci = 0; ci < 4; ci++){
    *(float4*)(agg + (size_t)b*8192 + (tc+ci)*128 + tf)     = make_float4(acc[ci][0],acc[ci][1],acc[ci][2],acc[ci][3]);
    *(float4*)(agg + (size_t)b*8192 + (tc+ci)*128 + tf + 4) = make_float4(acc[ci][4],acc[ci][5],acc[ci][6],acc[ci][7]);
  }
}

// ---------------- x_c = 0.5*(leaky(x+y0)+leaky(x+y1)) ----------------
__global__ void k_xc(const float* __restrict__ x, const float* __restrict__ y, float* __restrict__ xc){
  int i = blockIdx.x*256 + threadIdx.x;
  float xv = x[i];
  xc[i] = 0.5f*(lrelu(xv + y[i]) + lrelu(xv + y[NNODE*HD + i]));
}

// ---------------- fused: cluster-score softmax + exact top-52 + x_out gather ----------------
__global__ __launch_bounds__(256) void k_pool(const float* __restrict__ gb, const float* __restrict__ x,
                                              int* __restrict__ pidx, float* __restrict__ outB,
                                              float* __restrict__ outP, float* __restrict__ outX){
  int b = blockIdx.x, tid = threadIdx.x;
  __shared__ int pi[KK];
  __shared__ float pv[KK];
  if (tid < 64){
    float l = gb[b*64 + tid] + gb[NNODE + b*64 + tid];
    float m = l;
    #pragma unroll
    for (int off = 32; off; off >>= 1) m = fmaxf(m, __shfl_xor(m, off));
    float e = expf(l - m);
    float sm = e;
    #pragma unroll
    for (int off = 32; off; off >>= 1) sm += __shfl_xor(sm, off);
    float s = e/sm;
    int lane = tid;
    for (int t = 0; t < KK; t++){
      float v = s; int idx = lane;
      #pragma unroll
      for (int off = 32; off; off >>= 1){
        float ov = __shfl_xor(v, off); int oi = __shfl_xor(idx, off);
        if (ov > v || (ov == v && oi < idx)){ v = ov; idx = oi; }
      }
      if (lane == 0){
        pi[t] = idx; pv[t] = v;
        pidx[b*KK + t] = idx;
        outB[b*KK + t] = (float)b;
        outP[b*KK + t] = (float)(b*64 + idx);
      }
      if (lane == idx) s = -1e30f;
    }
  }
  __syncthreads();
  for (int o = tid*4; o < KK*HD; o += 1024){
    int j = o >> 7, f = o & 127;
    float4 xv = *(const float4*)(x + ((size_t)b*64 + pi[j])*HD + f);
    float sv = pv[j];
    *(float4*)(outX + (size_t)b*KK*HD + o) = make_float4(xv.x*sv, xv.y*sv, xv.z*sv, xv.w*sv);
  }
}

// ---------------- per-batch A2 block: S_p^T (A S_p), diag=1 ----------------
__global__ __launch_bounds__(256) void k_A2(const float* __restrict__ A_g, const float* __restrict__ S_g,
                                            const int* __restrict__ pidx, float* __restrict__ outA2){
  __shared__ __align__(16) float At[64*68];  // At[k][i] = A[i][k]
  __shared__ __align__(16) float Sp[64*56];  // Sp[k][t] = S[k][pc[t]] (t>=52 zero)
  __shared__ __align__(16) float T[64*56];   // T[i][t]
  __shared__ int pc[KK];
  int b = blockIdx.x, tid = threadIdx.x;
  if (tid < KK) pc[tid] = pidx[b*KK + tid];
  __syncthreads();
  for (int idx = tid; idx < 4096; idx += 256){
    int i = idx >> 6, k = idx & 63;
    At[k*68 + i] = A_g[b*4096 + idx];
  }
  for (int idx = tid; idx < 4096; idx += 256){
    int k = idx >> 6, t = idx & 63;
    if (t < 56) Sp[k*56 + t] = (t < KK) ? S_g[b*4096 + k*64 + pc[t]] : 0.f;
  }
  __syncthreads();
  if (tid < 224){
    int i0 = (tid/14)*4, t0 = (tid % 14)*4;
    float acc[4][4];
    #pragma unroll
    for (int a = 0; a < 4; a++)
      #pragma unroll
      for (int c = 0; c < 4; c++) acc[a][c] = 0.f;
    for (int k = 0; k < 64; k++){
      float4 a4 = *(const float4*)&At[k*68 + i0];
      float4 s4 = *(const float4*)&Sp[k*56 + t0];
      float a_[4] = {a4.x,a4.y,a4.z,a4.w};
      float s_[4] = {s4.x,s4.y,s4.z,s4.w};
      #pragma unroll
      for (int ii = 0; ii < 4; ii++)
        #pragma unroll
        for (int tt = 0; tt < 4; tt++) acc[ii][tt] += a_[ii]*s_[tt];
    }
    #pragma unroll
    for (int ii = 0; ii < 4; ii++)
      *(float4*)&T[(i0+ii)*56 + t0] = make_float4(acc[ii][0],acc[ii][1],acc[ii][2],acc[ii][3]);
  }
  __syncthreads();
  if (tid < 169){
    int a0 = (tid/13)*4, t0 = (tid % 13)*4;
    float acc[4][4];
    #pragma unroll
    for (int a = 0; a < 4; a++)
      #pragma unroll
      for (int c = 0; c < 4; c++) acc[a][c] = 0.f;
    for (int i = 0; i < 64; i++){
      float4 s4 = *(const float4*)&Sp[i*56 + a0];
      float4 t4 = *(const float4*)&T[i*56 + t0];
      float s_[4] = {s4.x,s4.y,s4.z,s4.w};
      float t_[4] = {t4.x,t4.y,t4.z,t4.w};
      #pragma unroll
      for (int aa = 0; aa < 4; aa++)
        #pragma unroll
        for (int tt = 0; tt < 4; tt++) acc[aa][tt] += s_[aa]*t_[tt];
    }
    #pragma unroll
    for (int aa = 0; aa < 4; aa++)
      #pragma unroll
      for (int tt = 0; tt < 4; tt++){
        int a = a0 + aa, t = t0 + tt;
        float v = (a == t) ? 1.f : acc[aa][tt];
        outA2[(size_t)(b*KK + a)*NKOUT + b*KK + t] = v;
      }
  }
}

extern "C" void kernel_launch(void* const* d_in, const int* in_sizes, int n_in,
                              void* d_out, int out_size, void* d_ws, size_t ws_size,
                              hipStream_t stream){
  const float* x    = (const float*)d_in[0];
  const int*   ei   = (const int*)d_in[1];
  const float* ew   = (const float*)d_in[2];
  const float* tgt  = (const float*)d_in[3];
  const float* Wk   = (const float*)d_in[5];
  const float* W1   = (const float*)d_in[6];
  const float* W2   = (const float*)d_in[7];
  const float* W3   = (const float*)d_in[8];
  const float* linW = (const float*)d_in[9];
  float* out = (float*)d_out;

  float* wf    = (float*)d_ws;
  float* A_g   = wf;                   // 262144
  float* M_g   = A_g + 262144;
  float* S_g   = M_g + 262144;
  float* xq    = S_g + 262144;         // 524288
  float* xq2   = xq + 524288;
  float* aggb  = xq2 + 524288;
  float* xc    = aggb + 524288;
  float* a_buf = xc + 524288;          // 2 x 524288
  float* h1    = a_buf + 1048576;      // 2 x 1048576
  float* h2    = h1 + 2097152;         // 2 x 524288 (also reused for y=agg@linW)
  float* fb    = h2 + 1048576;         // 2 x 4096
  float* gb    = fb + 8192;            // 2 x 4096
  int*   pidx  = (int*)(gb + 8192);    // NKOUT

  float* outX  = out;                          // 3328 x 128
  float* outA2 = out + 425984;                 // 3328 x 3328
  float* outB  = out + 425984 + 11075584;      // 3328
  float* outP  = outB + NKOUT;                 // 3328

  // 1. zero A2 region
  k_zero4<<<dim3(10816), dim3(256), 0, stream>>>((float4*)outA2, 2768896);
  // 2. dense per-batch normalized adjacency + multiplicity
  k_build<<<dim3(64), dim3(256), 0, stream>>>(ei, ew, A_g, M_g);
  // 3. x_q = hop(hop(x))
  k_hop2<<<dim3(64,2), dim3(256), 0, stream>>>(A_g, x, xq);
  // 4. attention pair f (kv=x; q: z0=x_q, z1=target)
  k_gemm<<<dim3(2,64,2), dim3(256), 0, stream>>>(x, Wk, a_buf, 128, 128, 0L, 16384L, 524288L, 0);
  k_gemm_h<<<dim3(4,64,2), dim3(256), 0, stream>>>(a_buf, xq, tgt, W1, h1);
  k_gemm<<<dim3(2,64,2), dim3(256), 0, stream>>>(h1, W2, h2, 256, 128, 1048576L, 32768L, 524288L, 1);
  k_w3sm<<<dim3(64,1,2), dim3(256), 0, stream>>>(h2, W3, fb);
  // 5. edge softmax -> S, agg
  k_edge<<<dim3(64), dim3(256), 0, stream>>>(M_g, fb, x, S_g, aggb);
  // 6. y = agg @ lin_W (2 heads), x_c
  k_gemm<<<dim3(2,64,2), dim3(256), 0, stream>>>(aggb, linW, h2, 128, 128, 0L, 16384L, 524288L, 0);
  k_xc<<<dim3(2048), dim3(256), 0, stream>>>(x, h2, xc);
  // 7. x_q2 = hop(hop(x_c))
  k_hop2<<<dim3(64,2), dim3(256), 0, stream>>>(A_g, xc, xq2);
  // 8. attention pair g (kv=x_c; q: z0=x_q2, z1=target)
  k_gemm<<<dim3(2,64,2), dim3(256), 0, stream>>>(xc, Wk + 2*16384, a_buf, 128, 128, 0L, 16384L, 524288L, 0);
  k_gemm_h<<<dim3(4,64,2), dim3(256), 0, stream>>>(a_buf, xq2, tgt, W1 + 2*131072, h1);
  k_gemm<<<dim3(2,64,2), dim3(256), 0, stream>>>(h1, W2 + 2*32768, h2, 256, 128, 1048576L, 32768L, 524288L, 1);
  k_w3sm<<<dim3(64,1,2), dim3(256), 0, stream>>>(h2, W3 + 2*128, gb);
  // 9. cluster score + top-k + x_out (fused)
  k_pool<<<dim3(64), dim3(256), 0, stream>>>(gb, x, pidx, outB, outP, outX);
  // 10. per-batch 52x52 blocks of A2
  k_A2<<<dim3(64), dim3(256), 0, stream>>>(A_g, S_g, pidx, outA2);
}